// Round 2
// baseline (422.533 us; speedup 1.0000x reference)
//
#include <hip/hip_runtime.h>
#include <hip/hip_bf16.h>

#define NNODES 50000
#define NEDGES 1600000
#define DIN    256
#define SUB    64
#define NBLK   196   // ceil(50000/256)

// ---------------- kernels ----------------

// 1) histogram of destination in-degrees
__global__ __launch_bounds__(256) void k_hist(const int* __restrict__ edges,
                                              int* __restrict__ cnt) {
    int e = blockIdx.x * 256 + threadIdx.x;
    if (e >= NEDGES) return;
    atomicAdd(&cnt[edges[NEDGES + e]], 1);
}

// 2a) per-256-chunk exclusive scan; chunk totals to bsum
__global__ __launch_bounds__(256) void k_scan1(const int* __restrict__ cnt,
                                               int* __restrict__ rowptr,
                                               int* __restrict__ bsum) {
    __shared__ int s[256];
    int t = threadIdx.x, i = blockIdx.x * 256 + t;
    int v = (i < NNODES) ? cnt[i] : 0;
    s[t] = v;
    __syncthreads();
    #pragma unroll
    for (int d = 1; d < 256; d <<= 1) {
        int w = (t >= d) ? s[t - d] : 0;
        __syncthreads();
        s[t] += w;
        __syncthreads();
    }
    if (i < NNODES) rowptr[i] = s[t] - v;      // exclusive
    if (t == 255) bsum[blockIdx.x] = s[t];     // inclusive total
}

// 2b) scan the 196 chunk totals (single block)
__global__ __launch_bounds__(256) void k_scan2(const int* __restrict__ bsum,
                                               int* __restrict__ boffs) {
    __shared__ int s[256];
    int t = threadIdx.x;
    int v = (t < NBLK) ? bsum[t] : 0;
    s[t] = v;
    __syncthreads();
    #pragma unroll
    for (int d = 1; d < 256; d <<= 1) {
        int w = (t >= d) ? s[t - d] : 0;
        __syncthreads();
        s[t] += w;
        __syncthreads();
    }
    boffs[t] = s[t] - v;   // exclusive
}

// 2c) add chunk offsets; produce rowptr and the atomic cursor copy
__global__ __launch_bounds__(256) void k_scan3(int* __restrict__ rowptr,
                                               const int* __restrict__ boffs,
                                               int* __restrict__ cursor) {
    int i = blockIdx.x * 256 + threadIdx.x;
    if (i >= NNODES) return;
    int v = rowptr[i] + boffs[blockIdx.x];
    rowptr[i] = v;
    cursor[i] = v;
}

// 3) dinv[n] = rsqrt(deg+1); x0s[n][f] = bf16( x[n][f] * dinv[n] )  (pre-scaled rows)
__global__ __launch_bounds__(256) void k_dinv_x0(const float* __restrict__ x,
                                                 const int* __restrict__ cnt,
                                                 float* __restrict__ dinv,
                                                 __hip_bfloat16* __restrict__ x0s) {
    int wave = threadIdx.x >> 6, lane = threadIdx.x & 63;
    int n = blockIdx.x * 4 + wave;         // grid 12500 * 4 = 50000 exactly
    float dc = rsqrtf((float)(cnt[n] + 1));
    if (lane == 0) dinv[n] = dc;
    x0s[n * SUB + lane] = __float2bfloat16(x[n * DIN + lane] * dc);
}

// 4) place edges into compact CSR (6.4 MB -> mostly L2-resident scatter)
__global__ __launch_bounds__(256) void k_place(const int* __restrict__ edges,
                                               int* __restrict__ cursor,
                                               int* __restrict__ csr) {
    int e = blockIdx.x * 256 + threadIdx.x;
    if (e >= NEDGES) return;
    int r = edges[e];
    int c = edges[NEDGES + e];
    int p = atomicAdd(&cursor[c], 1);
    csr[p] = r;
}

// 5) gather: one wave per node, lane = feature. Rows are pre-scaled by dinv[r].
__global__ __launch_bounds__(256) void k_gather(const __hip_bfloat16* __restrict__ x0s,
                                                const int* __restrict__ rowptr,
                                                const int* __restrict__ cnt,
                                                const float* __restrict__ dinv,
                                                const int* __restrict__ csr,
                                                float* __restrict__ agg) {
    int wave = threadIdx.x >> 6, lane = threadIdx.x & 63;
    int n = blockIdx.x * 4 + wave;
    int start = rowptr[n], len = cnt[n];
    float acc = __bfloat162float(x0s[n * SUB + lane]);   // self-loop (pre-scaled)
    const int* __restrict__ ix = csr + start;
    int e = 0;
    for (; e + 8 <= len; e += 8) {
        int r0 = ix[e + 0], r1 = ix[e + 1], r2 = ix[e + 2], r3 = ix[e + 3];
        int r4 = ix[e + 4], r5 = ix[e + 5], r6 = ix[e + 6], r7 = ix[e + 7];
        float v0 = __bfloat162float(x0s[r0 * SUB + lane]);
        float v1 = __bfloat162float(x0s[r1 * SUB + lane]);
        float v2 = __bfloat162float(x0s[r2 * SUB + lane]);
        float v3 = __bfloat162float(x0s[r3 * SUB + lane]);
        float v4 = __bfloat162float(x0s[r4 * SUB + lane]);
        float v5 = __bfloat162float(x0s[r5 * SUB + lane]);
        float v6 = __bfloat162float(x0s[r6 * SUB + lane]);
        float v7 = __bfloat162float(x0s[r7 * SUB + lane]);
        acc += ((v0 + v1) + (v2 + v3)) + ((v4 + v5) + (v6 + v7));
    }
    for (; e < len; ++e)
        acc += __bfloat162float(x0s[ix[e] * SUB + lane]);
    agg[n * SUB + lane] = acc * dinv[n];
}

// 6) per-head 64x64 linear + bias + relu; dual store (x_cat and heads are identical)
__global__ __launch_bounds__(256) void k_gemm(const float* __restrict__ agg,
                                              const float* __restrict__ W,
                                              const float* __restrict__ b,
                                              float* __restrict__ out0,
                                              float* __restrict__ out1) {
    int t = threadIdx.x;
    int h = t >> 6, o = t & 63;
    float wreg[64];
    #pragma unroll
    for (int f = 0; f < 64; ++f) wreg[f] = W[h * 4096 + f * 64 + o];
    float bias = b[t];
    int n0 = blockIdx.x * 8;   // 6250 * 8 = 50000 exactly
    for (int i = 0; i < 8; ++i) {
        int n = n0 + i;
        const float* __restrict__ arow = agg + n * SUB;   // block-uniform address
        float acc = bias;
        #pragma unroll
        for (int f = 0; f < 64; ++f) acc = fmaf(arow[f], wreg[f], acc);
        float v = fmaxf(acc, 0.0f);
        __builtin_nontemporal_store(v, &out0[n * 256 + t]);
        __builtin_nontemporal_store(v, &out1[n * 256 + t]);
    }
}

// ---------------- launch ----------------

extern "C" void kernel_launch(void* const* d_in, const int* in_sizes, int n_in,
                              void* d_out, int out_size, void* d_ws, size_t ws_size,
                              hipStream_t stream) {
    const float* x     = (const float*)d_in[0];   // (50000, 256) f32
    const int*   edges = (const int*)d_in[1];     // (2, 1600000) int
    const float* W     = (const float*)d_in[2];   // (4, 64, 64) f32
    const float* b     = (const float*)d_in[3];   // (4, 64) f32

    float* out0 = (float*)d_out;                   // x_cat (50000,256)
    float* out1 = out0 + (size_t)NNODES * 256;     // heads (50000,4,64) — same values

    // workspace layout (256B-aligned)
    char* ws = (char*)d_ws;
    int*            cnt    = (int*)(ws + 0);          // 200,000
    int*            rowptr = (int*)(ws + 200192);     // 200,000
    int*            cursor = (int*)(ws + 400384);     // 200,000
    float*          dinv   = (float*)(ws + 600576);   // 200,000
    int*            bsum   = (int*)(ws + 800768);     // 1,024
    int*            boffs  = (int*)(ws + 801792);     // 1,024
    int*            csr    = (int*)(ws + 802816);     // 6,400,000
    __hip_bfloat16* x0s    = (__hip_bfloat16*)(ws + 7202816);   // 6,400,000
    float*          agg    = (float*)(ws + 13602816); // 12,800,000  (total ~26.4 MB)

    hipMemsetAsync(cnt, 0, NNODES * sizeof(int), stream);
    k_hist   <<<(NEDGES + 255) / 256, 256, 0, stream>>>(edges, cnt);
    k_scan1  <<<NBLK, 256, 0, stream>>>(cnt, rowptr, bsum);
    k_scan2  <<<1, 256, 0, stream>>>(bsum, boffs);
    k_scan3  <<<NBLK, 256, 0, stream>>>(rowptr, boffs, cursor);
    k_dinv_x0<<<NNODES / 4, 256, 0, stream>>>(x, cnt, dinv, x0s);
    k_place  <<<(NEDGES + 255) / 256, 256, 0, stream>>>(edges, cursor, csr);
    k_gather <<<NNODES / 4, 256, 0, stream>>>(x0s, rowptr, cnt, dinv, csr, agg);
    k_gemm   <<<NNODES / 8, 256, 0, stream>>>(agg, W, b, out0, out1);
}